// Round 12
// baseline (1171.518 us; speedup 1.0000x reference)
//
// CTRNN MI355X — R12: 256-thread scan (1 wave/SIMD -> 512-reg budget), |R|=16 x |C|=64,
// 16-slot permuted reduce, 2 output rows/lane
#include <hip/hip_runtime.h>

#define T_STEPS 1024
#define BATCH   64
#define IDIM    128
#define HDIM    512
#define ALPHA_F 0.02f

typedef _Float16 half2_t __attribute__((ext_vector_type(2)));
typedef unsigned int uint32;

__device__ __forceinline__ float dot2f(uint32 w, uint32 h, float acc) {
#if __has_builtin(__builtin_amdgcn_fdot2)
  return __builtin_amdgcn_fdot2(__builtin_bit_cast(half2_t, w),
                                __builtin_bit_cast(half2_t, h), acc, false);
#else
  half2_t a = __builtin_bit_cast(half2_t, w);
  half2_t b = __builtin_bit_cast(half2_t, h);
  return acc + (float)a.x * (float)b.x + (float)a.y * (float)b.y;
#endif
}

__device__ __forceinline__ uint32 pk2(float a, float b) {
  auto p = __builtin_amdgcn_cvt_pkrtz(a, b);
  return __builtin_bit_cast(uint32, p);
}

__device__ __forceinline__ int dot4i8(uint32 a, uint32 b, int c) {
#if __has_builtin(__builtin_amdgcn_sdot4)
  return __builtin_amdgcn_sdot4((int)a, (int)b, c, false);
#else
  int s = c;
  s += (int)(signed char)(a)        * (int)(signed char)(b);
  s += (int)(signed char)(a >> 8)   * (int)(signed char)(b >> 8);
  s += (int)(signed char)(a >> 16)  * (int)(signed char)(b >> 16);
  s += (int)(signed char)(a >> 24)  * (int)(signed char)(b >> 24);
  return s;
#endif
}

__device__ __forceinline__ uint32 pkq(float v0, float v1, float v2, float v3, float inv) {
  int i0 = __float2int_rn(v0 * inv), i1 = __float2int_rn(v1 * inv);
  int i2 = __float2int_rn(v2 * inv), i3 = __float2int_rn(v3 * inv);
  return (uint32)(i0 & 255) | ((uint32)(i1 & 255) << 8) |
         ((uint32)(i2 & 255) << 16) | ((uint32)(i3 & 255) << 24);
}

__device__ __forceinline__ int dpp_xor1(int x) {
#if __has_builtin(__builtin_amdgcn_mov_dpp)
  return __builtin_amdgcn_mov_dpp(x, 0xB1, 0xF, 0xF, true);  // quad_perm [1,0,3,2]
#else
  return __shfl_xor(x, 1);
#endif
}
__device__ __forceinline__ int dpp_xor2(int x) {
#if __has_builtin(__builtin_amdgcn_mov_dpp)
  return __builtin_amdgcn_mov_dpp(x, 0x4E, 0xF, 0xF, true);  // quad_perm [2,3,0,1]
#else
  return __shfl_xor(x, 2);
#endif
}
__device__ __forceinline__ int swz_xor4(int x) {
#if __has_builtin(__builtin_amdgcn_ds_swizzle)
  return __builtin_amdgcn_ds_swizzle(x, 0x101F);  // BitMode xor=4
#else
  return __shfl_xor(x, 4);
#endif
}
__device__ __forceinline__ float fxor1(float x) {
  return __builtin_bit_cast(float, dpp_xor1(__builtin_bit_cast(int, x)));
}
__device__ __forceinline__ float fxor2(float x) {
  return __builtin_bit_cast(float, dpp_xor2(__builtin_bit_cast(int, x)));
}
__device__ __forceinline__ float fxor4(float x) {
  return __builtin_bit_cast(float, swz_xor4(__builtin_bit_cast(int, x)));
}

// ---------------------------------------------------------------------------
// x_proj kernel: xp[m][j] = sum_i x[m][i] * Win[j][i]  (f16 dot2)
// ---------------------------------------------------------------------------
__global__ __launch_bounds__(512) void ctrnn_proj(
    const float* __restrict__ x,    // [rows][128]
    const float* __restrict__ Win,  // [512][128]
    float* __restrict__ xp,         // [rows][512]
    int rows) {
  const int j = threadIdx.x;
  __shared__ __attribute__((aligned(16))) uint32 xb[8][64];

  uint32 w[64];
  const float2* wr = (const float2*)(Win + (size_t)j * IDIM);
#pragma unroll
  for (int p = 0; p < 64; ++p) {
    float2 f = wr[p];
    w[p] = pk2(f.x, f.y);
  }

  const int m0 = blockIdx.x * 128;
  for (int it = 0; it < 16; ++it) {
    const int mb = m0 + it * 8;
    __syncthreads();
    if (j < 256) {
      const int r = j >> 5, q = j & 31;
      const int m = mb + r;
      float4 v = make_float4(0.f, 0.f, 0.f, 0.f);
      if (m < rows) v = *(const float4*)(x + (size_t)m * IDIM + q * 4);
      xb[r][2 * q]     = pk2(v.x, v.y);
      xb[r][2 * q + 1] = pk2(v.z, v.w);
    }
    __syncthreads();
#pragma unroll
    for (int r = 0; r < 8; ++r) {
      const int m = mb + r;
      if (m < rows) {
        const uint4* xv = (const uint4*)xb[r];
        float a0 = 0.f, a1 = 0.f, a2 = 0.f, a3 = 0.f;
#pragma unroll
        for (int c = 0; c < 16; ++c) {
          uint4 hx = xv[c];
          a0 = dot2f(w[4 * c + 0], hx.x, a0);
          a1 = dot2f(w[4 * c + 1], hx.y, a1);
          a2 = dot2f(w[4 * c + 2], hx.z, a2);
          a3 = dot2f(w[4 * c + 3], hx.w, a3);
        }
        xp[(size_t)m * HDIM + j] = (a0 + a1) + (a2 + a3);
      }
    }
  }
}

// byte offset of h-row r in the padded LDS image (80B per 64-row group)
__device__ __forceinline__ int h_byte(int r) { return 80 * (r >> 6) + (r & 63); }

// ---------------------------------------------------------------------------
// scan kernel: 1 block/batch, 256 threads = 4 waves = 1 wave/SIMD.
// waves_per_eu(1,1): per-wave budget 512 unified regs -> w[256] resident
// (256 arch VGPRs + small AGPR spillover), no remat/reload tax.
// thread j: g = j&7 (col-eighth, 64 cols = 16 dwords), o = j>>3 (rows
// 16o..16o+15). Acc slot i (0..15) holds row 16o + 8*(i>>3) + ((i&7)^g);
// 3-round reduce (DPP xor1, DPP xor2, ds_swizzle xor4) lands full sums for
// rows 16o+g (slot 0) and 16o+8+g (slot 8) -> 2 output rows per lane.
// h mirror: i8 rows at byte 80*(r>>6)+(r&63): the 8 broadcast groups hit
// disjoint bank sets (20g mod 32 distinct) -> conflict-free b128 reads.
// ---------------------------------------------------------------------------
__global__ __launch_bounds__(256)
__attribute__((amdgpu_waves_per_eu(1, 1)))
void ctrnn_scan(
    const float* __restrict__ xp,  // [ct][BATCH][HDIM]
    const float* __restrict__ Wh,  // [512][512]
    const float* __restrict__ h0,  // [512]
    float* __restrict__ out,       // [T][B][H] then [B][H] final hidden
    int t0, int ct) {
  const int b = blockIdx.x;
  const int j = threadIdx.x;
  const int g = j & 7;
  const int o = j >> 3;
  const int n1 = 16 * o + g;       // slot-0 row
  const int n2 = n1 + 8;           // slot-8 row

  __shared__ __attribute__((aligned(16))) unsigned char hq[2][640];

  // ---- pass 1: per-slot local absmax over 64 cols ----
  float m[16];
#pragma unroll
  for (int i = 0; i < 16; ++i) {
    const int row = 16 * o + 8 * (i >> 3) + ((i & 7) ^ g);
    const float4* wr = (const float4*)(Wh + (size_t)row * HDIM + 64 * g);
    float mm = 0.f;
#pragma unroll
    for (int c = 0; c < 16; ++c) {
      float4 v = wr[c];
      mm = fmaxf(mm, fmaxf(fmaxf(fabsf(v.x), fabsf(v.y)), fmaxf(fabsf(v.z), fabsf(v.w))));
    }
    m[i] = mm;
  }
  // allreduce per row across the 8 lanes (slot-permuted partners)
  {
    float t[16];
#pragma unroll
    for (int i = 0; i < 16; ++i) t[i] = fmaxf(m[i], fxor1(m[i ^ 1]));
#pragma unroll
    for (int i = 0; i < 16; ++i) m[i] = fmaxf(t[i], fxor2(t[i ^ 2]));
#pragma unroll
    for (int i = 0; i < 16; ++i) t[i] = fmaxf(m[i], fxor4(m[i ^ 4]));
#pragma unroll
    for (int i = 0; i < 16; ++i) m[i] = t[i];
  }

  // ---- pass 2: quantize 16 row-slices (16 dwords each) into w[256] ----
  uint32 w[256];
#pragma unroll
  for (int i = 0; i < 16; ++i) {
    const float rm = m[i];
    const float inv = (rm > 0.f) ? 127.f / rm : 0.f;
    const int row = 16 * o + 8 * (i >> 3) + ((i & 7) ^ g);
    const float4* wr = (const float4*)(Wh + (size_t)row * HDIM + 64 * g);
#pragma unroll
    for (int c = 0; c < 16; ++c) {
      float4 v = wr[c];
      w[i * 16 + c] = pkq(v.x, v.y, v.z, v.w, inv);
    }
  }
  const float fscale1 = m[0] * (1.f / (127.f * 127.f));
  const float fscale2 = m[8] * (1.f / (127.f * 127.f));

  // ---- initial hidden: two rows per lane; i8 mirror into hq[0] ----
  float h1, h2;
  if (t0 == 0) { h1 = h0[n1]; h2 = h0[n2]; }
  else {
    const float* prev = out + ((size_t)(t0 - 1) * BATCH + b) * HDIM;
    h1 = prev[n1]; h2 = prev[n2];
  }
  {
    uint32 bA = (uint32)(__float2int_rn(h1 * 127.f) & 255);
    uint32 cA = bA | ((uint32)dpp_xor1((int)bA) << 8);
    uint32 dA = cA | ((uint32)dpp_xor2((int)cA) << 16);
    uint32 bB = (uint32)(__float2int_rn(h2 * 127.f) & 255);
    uint32 cB = bB | ((uint32)dpp_xor1((int)bB) << 8);
    uint32 dB = cB | ((uint32)dpp_xor2((int)cB) << 16);
    if (g == 0) {
      *((uint32*)&hq[0][h_byte(16 * o)])     = dA;
      *((uint32*)&hq[0][h_byte(16 * o + 8)]) = dB;
    } else if (g == 4) {
      *((uint32*)&hq[0][h_byte(16 * o + 4)])  = dA;
      *((uint32*)&hq[0][h_byte(16 * o + 12)]) = dB;
    }
  }
  __syncthreads();

  const float* xpp1 = xp + (size_t)b * HDIM + n1;
  const float* xpp2 = xp + (size_t)b * HDIM + n2;
  float* outp1 = out + ((size_t)t0 * BATCH + b) * HDIM + n1;
  float* outp2 = out + ((size_t)t0 * BATCH + b) * HDIM + n2;
  const size_t BH = (size_t)BATCH * HDIM;

  float xp1 = xpp1[0], xp2 = xpp2[0];
  int cur = 0;
  for (int t = 0; t < ct; ++t) {
    const size_t pre = (t + 1 < ct) ? BH : 0;
    const float xp1n = xpp1[pre];
    const float xp2n = xpp2[pre];

    const uint4* hb = (const uint4*)(&hq[cur][80 * g]);  // 4 x b128 = 64 h bytes
    int a[16];
#pragma unroll
    for (int i = 0; i < 16; ++i) a[i] = 0;
#pragma unroll
    for (int c = 0; c < 4; ++c) {
      uint4 hv = hb[c];
#pragma unroll
      for (int i = 0; i < 16; ++i) {
        a[i] = dot4i8(w[i * 16 + 4 * c + 0], hv.x, a[i]);
        a[i] = dot4i8(w[i * 16 + 4 * c + 1], hv.y, a[i]);
        a[i] = dot4i8(w[i * 16 + 4 * c + 2], hv.z, a[i]);
        a[i] = dot4i8(w[i * 16 + 4 * c + 3], hv.w, a[i]);
      }
    }
    // 3-round slot-permuted reduce; only the slots feeding rows n1, n2
    const int q0  = a[0]  + dpp_xor1(a[1]);
    const int q2  = a[2]  + dpp_xor1(a[3]);
    const int q4  = a[4]  + dpp_xor1(a[5]);
    const int q6  = a[6]  + dpp_xor1(a[7]);
    const int q8  = a[8]  + dpp_xor1(a[9]);
    const int q10 = a[10] + dpp_xor1(a[11]);
    const int q12 = a[12] + dpp_xor1(a[13]);
    const int q14 = a[14] + dpp_xor1(a[15]);
    const int r0  = q0  + dpp_xor2(q2);
    const int r4  = q4  + dpp_xor2(q6);
    const int r8  = q8  + dpp_xor2(q10);
    const int r12 = q12 + dpp_xor2(q14);
    const int s0  = r0  + swz_xor4(r4);
    const int s8  = r8  + swz_xor4(r12);

    const float z1 = (float)s0 * fscale1 + xp1;
    const float z2 = (float)s8 * fscale2 + xp2;
    const float sg1 = 1.0f / (1.0f + __expf(-z1));
    const float sg2 = 1.0f / (1.0f + __expf(-z2));
    h1 = h1 * (1.0f - ALPHA_F) + sg1 * ALPHA_F;
    h2 = h2 * (1.0f - ALPHA_F) + sg2 * ALPHA_F;

    *outp1 = h1;
    *outp2 = h2;

    uint32 bA = (uint32)(__float2int_rn(h1 * 127.f) & 255);
    uint32 cA = bA | ((uint32)dpp_xor1((int)bA) << 8);
    uint32 dA = cA | ((uint32)dpp_xor2((int)cA) << 16);
    uint32 bB = (uint32)(__float2int_rn(h2 * 127.f) & 255);
    uint32 cB = bB | ((uint32)dpp_xor1((int)bB) << 8);
    uint32 dB = cB | ((uint32)dpp_xor2((int)cB) << 16);
    if (g == 0) {
      *((uint32*)&hq[cur ^ 1][h_byte(16 * o)])     = dA;
      *((uint32*)&hq[cur ^ 1][h_byte(16 * o + 8)]) = dB;
    } else if (g == 4) {
      *((uint32*)&hq[cur ^ 1][h_byte(16 * o + 4)])  = dA;
      *((uint32*)&hq[cur ^ 1][h_byte(16 * o + 12)]) = dB;
    }
    __syncthreads();
    cur ^= 1;
    xp1 = xp1n; xp2 = xp2n;
    xpp1 += BH; xpp2 += BH;
    outp1 += BH; outp2 += BH;
  }

  if (t0 + ct == T_STEPS) {
    float* fin = out + (size_t)T_STEPS * BATCH * HDIM + (size_t)b * HDIM;
    fin[n1] = h1;
    fin[n2] = h2;
  }
}

// ---------------------------------------------------------------------------
extern "C" void kernel_launch(void* const* d_in, const int* in_sizes, int n_in,
                              void* d_out, int out_size, void* d_ws, size_t ws_size,
                              hipStream_t stream) {
  const float* x   = (const float*)d_in[0];
  const float* Win = (const float*)d_in[1];
  const float* Wh  = (const float*)d_in[2];
  const float* h0  = (const float*)d_in[3];
  float* out = (float*)d_out;
  float* xp  = (float*)d_ws;

  const size_t step_bytes = (size_t)BATCH * HDIM * sizeof(float);  // 128 KB
  int ct_max = (int)(ws_size / step_bytes);
  if (ct_max < 1) ct_max = 1;
  if (ct_max > T_STEPS) ct_max = T_STEPS;

  for (int t0 = 0; t0 < T_STEPS; t0 += ct_max) {
    const int ct = (T_STEPS - t0 < ct_max) ? (T_STEPS - t0) : ct_max;
    const int rows = ct * BATCH;
    const int nb = (rows + 127) / 128;
    hipLaunchKernelGGL(ctrnn_proj, dim3(nb), dim3(512), 0, stream,
                       x + (size_t)t0 * BATCH * IDIM, Win, xp, rows);
    hipLaunchKernelGGL(ctrnn_scan, dim3(BATCH), dim3(256), 0, stream,
                       xp, Wh, h0, out, t0, ct);
  }
}

// Round 13
// 1127.785 us; speedup vs baseline: 1.0388x; 1.0388x over previous
//
// CTRNN MI355X — R13: R11 geometry + 96-reg/64KB-LDS weight split (fit the 128-reg file)
#include <hip/hip_runtime.h>

#define T_STEPS 1024
#define BATCH   64
#define IDIM    128
#define HDIM    512
#define ALPHA_F 0.02f

typedef _Float16 half2_t __attribute__((ext_vector_type(2)));
typedef unsigned int uint32;

__device__ __forceinline__ float dot2f(uint32 w, uint32 h, float acc) {
#if __has_builtin(__builtin_amdgcn_fdot2)
  return __builtin_amdgcn_fdot2(__builtin_bit_cast(half2_t, w),
                                __builtin_bit_cast(half2_t, h), acc, false);
#else
  half2_t a = __builtin_bit_cast(half2_t, w);
  half2_t b = __builtin_bit_cast(half2_t, h);
  return acc + (float)a.x * (float)b.x + (float)a.y * (float)b.y;
#endif
}

__device__ __forceinline__ uint32 pk2(float a, float b) {
  auto p = __builtin_amdgcn_cvt_pkrtz(a, b);
  return __builtin_bit_cast(uint32, p);
}

__device__ __forceinline__ int dot4i8(uint32 a, uint32 b, int c) {
#if __has_builtin(__builtin_amdgcn_sdot4)
  return __builtin_amdgcn_sdot4((int)a, (int)b, c, false);
#else
  int s = c;
  s += (int)(signed char)(a)        * (int)(signed char)(b);
  s += (int)(signed char)(a >> 8)   * (int)(signed char)(b >> 8);
  s += (int)(signed char)(a >> 16)  * (int)(signed char)(b >> 16);
  s += (int)(signed char)(a >> 24)  * (int)(signed char)(b >> 24);
  return s;
#endif
}

__device__ __forceinline__ uint32 pkq(float v0, float v1, float v2, float v3, float inv) {
  int i0 = __float2int_rn(v0 * inv), i1 = __float2int_rn(v1 * inv);
  int i2 = __float2int_rn(v2 * inv), i3 = __float2int_rn(v3 * inv);
  return (uint32)(i0 & 255) | ((uint32)(i1 & 255) << 8) |
         ((uint32)(i2 & 255) << 16) | ((uint32)(i3 & 255) << 24);
}

__device__ __forceinline__ int dpp_xor1(int x) {
#if __has_builtin(__builtin_amdgcn_mov_dpp)
  return __builtin_amdgcn_mov_dpp(x, 0xB1, 0xF, 0xF, true);  // quad_perm [1,0,3,2]
#else
  return __shfl_xor(x, 1);
#endif
}
__device__ __forceinline__ int dpp_xor2(int x) {
#if __has_builtin(__builtin_amdgcn_mov_dpp)
  return __builtin_amdgcn_mov_dpp(x, 0x4E, 0xF, 0xF, true);  // quad_perm [2,3,0,1]
#else
  return __shfl_xor(x, 2);
#endif
}
__device__ __forceinline__ int swz_xor4(int x) {
#if __has_builtin(__builtin_amdgcn_ds_swizzle)
  return __builtin_amdgcn_ds_swizzle(x, 0x101F);  // BitMode xor=4
#else
  return __shfl_xor(x, 4);
#endif
}
__device__ __forceinline__ float fxor1(float x) {
  return __builtin_bit_cast(float, dpp_xor1(__builtin_bit_cast(int, x)));
}
__device__ __forceinline__ float fxor2(float x) {
  return __builtin_bit_cast(float, dpp_xor2(__builtin_bit_cast(int, x)));
}
__device__ __forceinline__ float fxor4(float x) {
  return __builtin_bit_cast(float, swz_xor4(__builtin_bit_cast(int, x)));
}

// ---------------------------------------------------------------------------
// x_proj kernel: xp[m][j] = sum_i x[m][i] * Win[j][i]  (f16 dot2)
// ---------------------------------------------------------------------------
__global__ __launch_bounds__(512) void ctrnn_proj(
    const float* __restrict__ x,    // [rows][128]
    const float* __restrict__ Win,  // [512][128]
    float* __restrict__ xp,         // [rows][512]
    int rows) {
  const int j = threadIdx.x;
  __shared__ __attribute__((aligned(16))) uint32 xb[8][64];

  uint32 w[64];
  const float2* wr = (const float2*)(Win + (size_t)j * IDIM);
#pragma unroll
  for (int p = 0; p < 64; ++p) {
    float2 f = wr[p];
    w[p] = pk2(f.x, f.y);
  }

  const int m0 = blockIdx.x * 128;
  for (int it = 0; it < 16; ++it) {
    const int mb = m0 + it * 8;
    __syncthreads();
    if (j < 256) {
      const int r = j >> 5, q = j & 31;
      const int m = mb + r;
      float4 v = make_float4(0.f, 0.f, 0.f, 0.f);
      if (m < rows) v = *(const float4*)(x + (size_t)m * IDIM + q * 4);
      xb[r][2 * q]     = pk2(v.x, v.y);
      xb[r][2 * q + 1] = pk2(v.z, v.w);
    }
    __syncthreads();
#pragma unroll
    for (int r = 0; r < 8; ++r) {
      const int m = mb + r;
      if (m < rows) {
        const uint4* xv = (const uint4*)xb[r];
        float a0 = 0.f, a1 = 0.f, a2 = 0.f, a3 = 0.f;
#pragma unroll
        for (int c = 0; c < 16; ++c) {
          uint4 hx = xv[c];
          a0 = dot2f(w[4 * c + 0], hx.x, a0);
          a1 = dot2f(w[4 * c + 1], hx.y, a1);
          a2 = dot2f(w[4 * c + 2], hx.z, a2);
          a3 = dot2f(w[4 * c + 3], hx.w, a3);
        }
        xp[(size_t)m * HDIM + j] = (a0 + a1) + (a2 + a3);
      }
    }
  }
}

// ---------------------------------------------------------------------------
// scan kernel: 1 block/batch, 512 threads (2 waves/SIMD -> 128-reg grant).
// R11 slot-permuted geometry: g = j&7 (col-eighth), o = j>>3; acc slot i
// holds row 8o+(i^g); 7-exchange DPP/swizzle reduce; own row -> slot 0.
// Weight split to FIT the file: per slot, cols 0..47 in 12 register dwords
// (w[96]); cols 48..63 in LDS wl[8][512] (uint4/thread/slot, consecutive-16B
// conflict-free reads, 2-deep ping-pong prefetch).
// h mirror: i8, row r at byte 80*(r>>6)+(r&63) (conflict-free broadcast).
// ---------------------------------------------------------------------------
#define REGD(acc, i)                                  \
  acc = dot4i8(w[(i)*12 + 0], hv0.x, acc);            \
  acc = dot4i8(w[(i)*12 + 1], hv0.y, acc);            \
  acc = dot4i8(w[(i)*12 + 2], hv0.z, acc);            \
  acc = dot4i8(w[(i)*12 + 3], hv0.w, acc);            \
  acc = dot4i8(w[(i)*12 + 4], hv1.x, acc);            \
  acc = dot4i8(w[(i)*12 + 5], hv1.y, acc);            \
  acc = dot4i8(w[(i)*12 + 6], hv1.z, acc);            \
  acc = dot4i8(w[(i)*12 + 7], hv1.w, acc);            \
  acc = dot4i8(w[(i)*12 + 8], hv2.x, acc);            \
  acc = dot4i8(w[(i)*12 + 9], hv2.y, acc);            \
  acc = dot4i8(w[(i)*12 +10], hv2.z, acc);            \
  acc = dot4i8(w[(i)*12 +11], hv2.w, acc);

#define LDSD(acc, wv)                                 \
  acc = dot4i8(wv.x, hv3.x, acc);                     \
  acc = dot4i8(wv.y, hv3.y, acc);                     \
  acc = dot4i8(wv.z, hv3.z, acc);                     \
  acc = dot4i8(wv.w, hv3.w, acc);

__global__ __launch_bounds__(512)
__attribute__((amdgpu_waves_per_eu(2, 2)))
void ctrnn_scan(
    const float* __restrict__ xp,  // [ct][BATCH][HDIM]
    const float* __restrict__ Wh,  // [512][512]
    const float* __restrict__ h0,  // [512]
    float* __restrict__ out,       // [T][B][H] then [B][H] final hidden
    int t0, int ct) {
  const int b = blockIdx.x;
  const int j = threadIdx.x;   // == output row n
  const int g = j & 7;
  const int o = j >> 3;

  __shared__ __attribute__((aligned(16))) uint4 wl[8][512];          // 64 KB
  __shared__ __attribute__((aligned(16))) unsigned char hq[2][640];

  // ---- pass 1: per-slot local absmax over 64 cols (slot i <-> row 8o+(i^g)) ----
  float m[8];
#pragma unroll
  for (int i = 0; i < 8; ++i) {
    const float4* wr = (const float4*)(Wh + (size_t)(8 * o + (i ^ g)) * HDIM + 64 * g);
    float mm = 0.f;
#pragma unroll
    for (int c = 0; c < 16; ++c) {
      float4 v = wr[c];
      mm = fmaxf(mm, fmaxf(fmaxf(fabsf(v.x), fabsf(v.y)), fmaxf(fabsf(v.z), fabsf(v.w))));
    }
    m[i] = mm;
  }
  {  // allreduce per row across the 8 lanes (slot-permuted partners)
    float t[8];
#pragma unroll
    for (int i = 0; i < 8; ++i) t[i] = fmaxf(m[i], fxor1(m[i ^ 1]));
#pragma unroll
    for (int i = 0; i < 8; ++i) m[i] = fmaxf(t[i], fxor2(t[i ^ 2]));
#pragma unroll
    for (int i = 0; i < 8; ++i) t[i] = fmaxf(m[i], fxor4(m[i ^ 4]));
#pragma unroll
    for (int i = 0; i < 8; ++i) m[i] = t[i];
  }

  // ---- pass 2: quantize; cols 0..47 -> w[96] regs, cols 48..63 -> wl LDS ----
  uint32 w[96];
#pragma unroll
  for (int i = 0; i < 8; ++i) {
    const float rm = m[i];
    const float inv = (rm > 0.f) ? 127.f / rm : 0.f;
    const float4* wr = (const float4*)(Wh + (size_t)(8 * o + (i ^ g)) * HDIM + 64 * g);
#pragma unroll
    for (int c = 0; c < 12; ++c) {
      float4 v = wr[c];
      w[i * 12 + c] = pkq(v.x, v.y, v.z, v.w, inv);
    }
    float4 vA = wr[12], vB = wr[13], vC = wr[14], vD = wr[15];
    wl[i][j] = make_uint4(pkq(vA.x, vA.y, vA.z, vA.w, inv),
                          pkq(vB.x, vB.y, vB.z, vB.w, inv),
                          pkq(vC.x, vC.y, vC.z, vC.w, inv),
                          pkq(vD.x, vD.y, vD.z, vD.w, inv));
  }
  const float fscale = m[0] * (1.f / (127.f * 127.f));  // own row == slot 0

  // ---- initial hidden: h (f32) in register, i8 mirror packed into hq[0] ----
  float h;
  if (t0 == 0) h = h0[j];
  else h = out[((size_t)(t0 - 1) * BATCH + b) * HDIM + j];
  {
    uint32 bb = (uint32)(__float2int_rn(h * 127.f) & 255);
    uint32 c1 = bb | ((uint32)dpp_xor1((int)bb) << 8);
    uint32 dw = c1 | ((uint32)dpp_xor2((int)c1) << 16);
    if ((j & 3) == 0) *((uint32*)&hq[0][j + 16 * (j >> 6)]) = dw;
  }
  __syncthreads();  // covers wl + hq[0]

  const float* xpp = xp + (size_t)b * HDIM + j;
  float* outp = out + ((size_t)t0 * BATCH + b) * HDIM + j;
  const size_t BH = (size_t)BATCH * HDIM;

  int cur = 0;
  for (int t = 0; t < ct; ++t) {
    const float xp_c = *xpp;  // L2-hit; latency hides under the dot phase

    const uint4* hb = (const uint4*)(&hq[cur][80 * g]);
    const uint4 hv0 = hb[0], hv1 = hb[1], hv2 = hb[2], hv3 = hb[3];

    uint4 wvA = wl[0][j];
    uint4 wvB = wl[1][j];
    int a0 = 0, a1 = 0, a2 = 0, a3 = 0, a4 = 0, a5 = 0, a6 = 0, a7 = 0;
    REGD(a0, 0) LDSD(a0, wvA) wvA = wl[2][j];
    REGD(a1, 1) LDSD(a1, wvB) wvB = wl[3][j];
    REGD(a2, 2) LDSD(a2, wvA) wvA = wl[4][j];
    REGD(a3, 3) LDSD(a3, wvB) wvB = wl[5][j];
    REGD(a4, 4) LDSD(a4, wvA) wvA = wl[6][j];
    REGD(a5, 5) LDSD(a5, wvB) wvB = wl[7][j];
    REGD(a6, 6) LDSD(a6, wvA)
    REGD(a7, 7) LDSD(a7, wvB)

    // 7-exchange tree (own row ends in slot 0)
    const int q0 = a0 + dpp_xor1(a1);
    const int q1 = a2 + dpp_xor1(a3);
    const int q2 = a4 + dpp_xor1(a5);
    const int q3 = a6 + dpp_xor1(a7);
    const int r0 = q0 + dpp_xor2(q1);
    const int r1 = q2 + dpp_xor2(q3);
    const int res = r0 + swz_xor4(r1);

    const float z = (float)res * fscale + xp_c;
    const float s = 1.0f / (1.0f + __expf(-z));
    h = h * (1.0f - ALPHA_F) + s * ALPHA_F;

    *outp = h;  // coalesced 512 x 4B

    uint32 bb = (uint32)(__float2int_rn(h * 127.f) & 255);
    uint32 c1 = bb | ((uint32)dpp_xor1((int)bb) << 8);
    uint32 dw = c1 | ((uint32)dpp_xor2((int)c1) << 16);
    if ((j & 3) == 0) *((uint32*)&hq[cur ^ 1][j + 16 * (j >> 6)]) = dw;
    __syncthreads();
    cur ^= 1;
    xpp += BH;
    outp += BH;
  }

  if (t0 + ct == T_STEPS) {
    out[(size_t)T_STEPS * BATCH * HDIM + (size_t)b * HDIM + j] = h;
  }
}

// ---------------------------------------------------------------------------
extern "C" void kernel_launch(void* const* d_in, const int* in_sizes, int n_in,
                              void* d_out, int out_size, void* d_ws, size_t ws_size,
                              hipStream_t stream) {
  const float* x   = (const float*)d_in[0];
  const float* Win = (const float*)d_in[1];
  const float* Wh  = (const float*)d_in[2];
  const float* h0  = (const float*)d_in[3];
  float* out = (float*)d_out;
  float* xp  = (float*)d_ws;

  const size_t step_bytes = (size_t)BATCH * HDIM * sizeof(float);  // 128 KB
  int ct_max = (int)(ws_size / step_bytes);
  if (ct_max < 1) ct_max = 1;
  if (ct_max > T_STEPS) ct_max = T_STEPS;

  for (int t0 = 0; t0 < T_STEPS; t0 += ct_max) {
    const int ct = (T_STEPS - t0 < ct_max) ? (T_STEPS - t0) : ct_max;
    const int rows = ct * BATCH;
    const int nb = (rows + 127) / 128;
    hipLaunchKernelGGL(ctrnn_proj, dim3(nb), dim3(512), 0, stream,
                       x + (size_t)t0 * BATCH * IDIM, Win, xp, rows);
    hipLaunchKernelGGL(ctrnn_scan, dim3(BATCH), dim3(512), 0, stream,
                       xp, Wh, h0, out, t0, ct);
  }
}

// Round 14
// 918.485 us; speedup vs baseline: 1.2755x; 1.2279x over previous
//
// CTRNN MI355X — R14: R11 structure + serial-tail cuts (b8 h-write, post-barrier store, exp2 fuse)
#include <hip/hip_runtime.h>

#define T_STEPS 1024
#define BATCH   64
#define IDIM    128
#define HDIM    512
#define ALPHA_F 0.02f
#define NLOG2E  (-1.4426950408889634f)

typedef _Float16 half2_t __attribute__((ext_vector_type(2)));
typedef unsigned int uint32;

__device__ __forceinline__ float dot2f(uint32 w, uint32 h, float acc) {
#if __has_builtin(__builtin_amdgcn_fdot2)
  return __builtin_amdgcn_fdot2(__builtin_bit_cast(half2_t, w),
                                __builtin_bit_cast(half2_t, h), acc, false);
#else
  half2_t a = __builtin_bit_cast(half2_t, w);
  half2_t b = __builtin_bit_cast(half2_t, h);
  return acc + (float)a.x * (float)b.x + (float)a.y * (float)b.y;
#endif
}

__device__ __forceinline__ uint32 pk2(float a, float b) {
  auto p = __builtin_amdgcn_cvt_pkrtz(a, b);
  return __builtin_bit_cast(uint32, p);
}

__device__ __forceinline__ int dot4i8(uint32 a, uint32 b, int c) {
#if __has_builtin(__builtin_amdgcn_sdot4)
  return __builtin_amdgcn_sdot4((int)a, (int)b, c, false);
#else
  int s = c;
  s += (int)(signed char)(a)        * (int)(signed char)(b);
  s += (int)(signed char)(a >> 8)   * (int)(signed char)(b >> 8);
  s += (int)(signed char)(a >> 16)  * (int)(signed char)(b >> 16);
  s += (int)(signed char)(a >> 24)  * (int)(signed char)(b >> 24);
  return s;
#endif
}

__device__ __forceinline__ uint32 pkq(float v0, float v1, float v2, float v3, float inv) {
  int i0 = __float2int_rn(v0 * inv), i1 = __float2int_rn(v1 * inv);
  int i2 = __float2int_rn(v2 * inv), i3 = __float2int_rn(v3 * inv);
  return (uint32)(i0 & 255) | ((uint32)(i1 & 255) << 8) |
         ((uint32)(i2 & 255) << 16) | ((uint32)(i3 & 255) << 24);
}

__device__ __forceinline__ int dpp_xor1(int x) {
#if __has_builtin(__builtin_amdgcn_mov_dpp)
  return __builtin_amdgcn_mov_dpp(x, 0xB1, 0xF, 0xF, true);  // quad_perm [1,0,3,2]
#else
  return __shfl_xor(x, 1);
#endif
}
__device__ __forceinline__ int dpp_xor2(int x) {
#if __has_builtin(__builtin_amdgcn_mov_dpp)
  return __builtin_amdgcn_mov_dpp(x, 0x4E, 0xF, 0xF, true);  // quad_perm [2,3,0,1]
#else
  return __shfl_xor(x, 2);
#endif
}
__device__ __forceinline__ int swz_xor4(int x) {
#if __has_builtin(__builtin_amdgcn_ds_swizzle)
  return __builtin_amdgcn_ds_swizzle(x, 0x101F);  // BitMode xor=4
#else
  return __shfl_xor(x, 4);
#endif
}
__device__ __forceinline__ float fxor1(float x) {
  return __builtin_bit_cast(float, dpp_xor1(__builtin_bit_cast(int, x)));
}
__device__ __forceinline__ float fxor2(float x) {
  return __builtin_bit_cast(float, dpp_xor2(__builtin_bit_cast(int, x)));
}
__device__ __forceinline__ float fxor4(float x) {
  return __builtin_bit_cast(float, swz_xor4(__builtin_bit_cast(int, x)));
}

// ---------------------------------------------------------------------------
// x_proj kernel: xpT[m][j] = NLOG2E * sum_i x[m][i] * Win[j][i]
// (pre-scaled by -log2(e) so the scan's sigmoid uses exp2 directly)
// ---------------------------------------------------------------------------
__global__ __launch_bounds__(512) void ctrnn_proj(
    const float* __restrict__ x,    // [rows][128]
    const float* __restrict__ Win,  // [512][128]
    float* __restrict__ xp,         // [rows][512], pre-scaled
    int rows) {
  const int j = threadIdx.x;
  __shared__ __attribute__((aligned(16))) uint32 xb[8][64];

  uint32 w[64];
  const float2* wr = (const float2*)(Win + (size_t)j * IDIM);
#pragma unroll
  for (int p = 0; p < 64; ++p) {
    float2 f = wr[p];
    w[p] = pk2(f.x, f.y);
  }

  const int m0 = blockIdx.x * 128;
  for (int it = 0; it < 16; ++it) {
    const int mb = m0 + it * 8;
    __syncthreads();
    if (j < 256) {
      const int r = j >> 5, q = j & 31;
      const int m = mb + r;
      float4 v = make_float4(0.f, 0.f, 0.f, 0.f);
      if (m < rows) v = *(const float4*)(x + (size_t)m * IDIM + q * 4);
      xb[r][2 * q]     = pk2(v.x, v.y);
      xb[r][2 * q + 1] = pk2(v.z, v.w);
    }
    __syncthreads();
#pragma unroll
    for (int r = 0; r < 8; ++r) {
      const int m = mb + r;
      if (m < rows) {
        const uint4* xv = (const uint4*)xb[r];
        float a0 = 0.f, a1 = 0.f, a2 = 0.f, a3 = 0.f;
#pragma unroll
        for (int c = 0; c < 16; ++c) {
          uint4 hx = xv[c];
          a0 = dot2f(w[4 * c + 0], hx.x, a0);
          a1 = dot2f(w[4 * c + 1], hx.y, a1);
          a2 = dot2f(w[4 * c + 2], hx.z, a2);
          a3 = dot2f(w[4 * c + 3], hx.w, a3);
        }
        xp[(size_t)m * HDIM + j] = NLOG2E * ((a0 + a1) + (a2 + a3));
      }
    }
  }
}

// ---------------------------------------------------------------------------
// scan kernel (R11 structure): 1 block/batch, 512 threads (2 waves/SIMD).
// thread j: g = j&7 (col-eighth, 64 cols = 16 i8 dwords), o = j>>3 (rows
// 8o..8o+7); acc slot i holds row 8o+(i^g); 7-exchange DPP/swizzle reduce;
// own row lands in slot 0. h mirror: i8, row r at byte r+16*(r>>6).
// R14 deltas: (1) h-pack replaced by direct per-lane ds_write_b8 (cuts the
// serial DPP chain pre-barrier); (2) out-store moved after the barrier
// (issues under next step's dots); (3) sigmoid via exp2 with pre-scaled xp.
// ---------------------------------------------------------------------------
__global__ __launch_bounds__(512)
__attribute__((amdgpu_waves_per_eu(2, 2)))
void ctrnn_scan(
    const float* __restrict__ xp,  // [ct][BATCH][HDIM], pre-scaled by -log2e
    const float* __restrict__ Wh,  // [512][512]
    const float* __restrict__ h0,  // [512]
    float* __restrict__ out,       // [T][B][H] then [B][H] final hidden
    int t0, int ct) {
  const int b = blockIdx.x;
  const int j = threadIdx.x;   // == output row n
  const int g = j & 7;
  const int o = j >> 3;

  __shared__ __attribute__((aligned(16))) unsigned char hq[2][640];

  // ---- pass 1: per-slot local absmax over 64 cols (slot i <-> row 8o+(i^g)) ----
  float m[8];
#pragma unroll
  for (int i = 0; i < 8; ++i) {
    const float4* wr = (const float4*)(Wh + (size_t)(8 * o + (i ^ g)) * HDIM + 64 * g);
    float mm = 0.f;
#pragma unroll
    for (int c = 0; c < 16; ++c) {
      float4 v = wr[c];
      mm = fmaxf(mm, fmaxf(fmaxf(fabsf(v.x), fabsf(v.y)), fmaxf(fabsf(v.z), fabsf(v.w))));
    }
    m[i] = mm;
  }
  {  // allreduce per row across the 8 lanes (slot-permuted partners)
    float t[8];
#pragma unroll
    for (int i = 0; i < 8; ++i) t[i] = fmaxf(m[i], fxor1(m[i ^ 1]));
#pragma unroll
    for (int i = 0; i < 8; ++i) m[i] = fmaxf(t[i], fxor2(t[i ^ 2]));
#pragma unroll
    for (int i = 0; i < 8; ++i) t[i] = fmaxf(m[i], fxor4(m[i ^ 4]));
#pragma unroll
    for (int i = 0; i < 8; ++i) m[i] = t[i];
  }

  // ---- pass 2: quantize 8 row-slices (16 dwords each) into w[128] ----
  uint32 w[128];
#pragma unroll
  for (int i = 0; i < 8; ++i) {
    const float rm = m[i];
    const float inv = (rm > 0.f) ? 127.f / rm : 0.f;
    const float4* wr = (const float4*)(Wh + (size_t)(8 * o + (i ^ g)) * HDIM + 64 * g);
#pragma unroll
    for (int c = 0; c < 16; ++c) {
      float4 v = wr[c];
      w[i * 16 + c] = pkq(v.x, v.y, v.z, v.w, inv);
    }
  }
  // a = -log2e * fscale (own row == slot 0); xp already pre-scaled
  const float afac = m[0] * (1.f / (127.f * 127.f)) * NLOG2E;

  // ---- initial hidden: h (f32) in register, i8 mirror via b8 write ----
  float h;
  if (t0 == 0) h = h0[j];
  else h = out[((size_t)(t0 - 1) * BATCH + b) * HDIM + j];
  hq[0][j + 16 * (j >> 6)] = (unsigned char)(__float2int_rn(h * 127.f));
  __syncthreads();

  const float* xpp = xp + (size_t)b * HDIM + j;
  float* outp = out + ((size_t)t0 * BATCH + b) * HDIM + j;
  const size_t BH = (size_t)BATCH * HDIM;

  int cur = 0;
  for (int t = 0; t < ct; ++t) {
    const float xpw = *xpp;  // pre-scaled; L2 latency hides under dots

    const uint4* hb = (const uint4*)(&hq[cur][80 * g]);
    const uint4 hv0 = hb[0], hv1 = hb[1], hv2 = hb[2], hv3 = hb[3];
    int a0 = 0, a1 = 0, a2 = 0, a3 = 0, a4 = 0, a5 = 0, a6 = 0, a7 = 0;
#pragma unroll
    for (int c = 0; c < 4; ++c) {
      const uint4 hv = (c == 0) ? hv0 : (c == 1) ? hv1 : (c == 2) ? hv2 : hv3;
      a0 = dot4i8(w[0 * 16 + 4 * c + 0], hv.x, a0);
      a0 = dot4i8(w[0 * 16 + 4 * c + 1], hv.y, a0);
      a0 = dot4i8(w[0 * 16 + 4 * c + 2], hv.z, a0);
      a0 = dot4i8(w[0 * 16 + 4 * c + 3], hv.w, a0);
      a1 = dot4i8(w[1 * 16 + 4 * c + 0], hv.x, a1);
      a1 = dot4i8(w[1 * 16 + 4 * c + 1], hv.y, a1);
      a1 = dot4i8(w[1 * 16 + 4 * c + 2], hv.z, a1);
      a1 = dot4i8(w[1 * 16 + 4 * c + 3], hv.w, a1);
      a2 = dot4i8(w[2 * 16 + 4 * c + 0], hv.x, a2);
      a2 = dot4i8(w[2 * 16 + 4 * c + 1], hv.y, a2);
      a2 = dot4i8(w[2 * 16 + 4 * c + 2], hv.z, a2);
      a2 = dot4i8(w[2 * 16 + 4 * c + 3], hv.w, a2);
      a3 = dot4i8(w[3 * 16 + 4 * c + 0], hv.x, a3);
      a3 = dot4i8(w[3 * 16 + 4 * c + 1], hv.y, a3);
      a3 = dot4i8(w[3 * 16 + 4 * c + 2], hv.z, a3);
      a3 = dot4i8(w[3 * 16 + 4 * c + 3], hv.w, a3);
      a4 = dot4i8(w[4 * 16 + 4 * c + 0], hv.x, a4);
      a4 = dot4i8(w[4 * 16 + 4 * c + 1], hv.y, a4);
      a4 = dot4i8(w[4 * 16 + 4 * c + 2], hv.z, a4);
      a4 = dot4i8(w[4 * 16 + 4 * c + 3], hv.w, a4);
      a5 = dot4i8(w[5 * 16 + 4 * c + 0], hv.x, a5);
      a5 = dot4i8(w[5 * 16 + 4 * c + 1], hv.y, a5);
      a5 = dot4i8(w[5 * 16 + 4 * c + 2], hv.z, a5);
      a5 = dot4i8(w[5 * 16 + 4 * c + 3], hv.w, a5);
      a6 = dot4i8(w[6 * 16 + 4 * c + 0], hv.x, a6);
      a6 = dot4i8(w[6 * 16 + 4 * c + 1], hv.y, a6);
      a6 = dot4i8(w[6 * 16 + 4 * c + 2], hv.z, a6);
      a6 = dot4i8(w[6 * 16 + 4 * c + 3], hv.w, a6);
      a7 = dot4i8(w[7 * 16 + 4 * c + 0], hv.x, a7);
      a7 = dot4i8(w[7 * 16 + 4 * c + 1], hv.y, a7);
      a7 = dot4i8(w[7 * 16 + 4 * c + 2], hv.z, a7);
      a7 = dot4i8(w[7 * 16 + 4 * c + 3], hv.w, a7);
    }
    // 7-exchange tree (own row ends in slot 0)
    const int q0 = a0 + dpp_xor1(a1);
    const int q1 = a2 + dpp_xor1(a3);
    const int q2 = a4 + dpp_xor1(a5);
    const int q3 = a6 + dpp_xor1(a7);
    const int r0 = q0 + dpp_xor2(q1);
    const int r1 = q2 + dpp_xor2(q3);
    const int res = r0 + swz_xor4(r1);

    // sigmoid via exp2: e = 2^(a*res + xpw) == e^{-z}
    const float e = exp2f((float)res * afac + xpw);
    const float s = 1.0f / (1.0f + e);
    h = h * (1.0f - ALPHA_F) + s * ALPHA_F;

    // i8 mirror write (single byte, no pack chain) BEFORE barrier
    hq[cur ^ 1][j + 16 * (j >> 6)] = (unsigned char)(__float2int_rn(h * 127.f));
    __syncthreads();

    *outp = h;  // after barrier: issues in the shadow of next step's dots
    cur ^= 1;
    xpp += BH;
    outp += BH;
  }

  if (t0 + ct == T_STEPS) {
    out[(size_t)T_STEPS * BATCH * HDIM + (size_t)b * HDIM + j] = h;
  }
}

// ---------------------------------------------------------------------------
extern "C" void kernel_launch(void* const* d_in, const int* in_sizes, int n_in,
                              void* d_out, int out_size, void* d_ws, size_t ws_size,
                              hipStream_t stream) {
  const float* x   = (const float*)d_in[0];
  const float* Win = (const float*)d_in[1];
  const float* Wh  = (const float*)d_in[2];
  const float* h0  = (const float*)d_in[3];
  float* out = (float*)d_out;
  float* xp  = (float*)d_ws;

  const size_t step_bytes = (size_t)BATCH * HDIM * sizeof(float);  // 128 KB
  int ct_max = (int)(ws_size / step_bytes);
  if (ct_max < 1) ct_max = 1;
  if (ct_max > T_STEPS) ct_max = T_STEPS;

  for (int t0 = 0; t0 < T_STEPS; t0 += ct_max) {
    const int ct = (T_STEPS - t0 < ct_max) ? (T_STEPS - t0) : ct_max;
    const int rows = ct * BATCH;
    const int nb = (rows + 127) / 128;
    hipLaunchKernelGGL(ctrnn_proj, dim3(nb), dim3(512), 0, stream,
                       x + (size_t)t0 * BATCH * IDIM, Win, xp, rows);
    hipLaunchKernelGGL(ctrnn_scan, dim3(BATCH), dim3(512), 0, stream,
                       xp, Wh, h0, out, t0, ct);
  }
}

// Round 15
// 884.749 us; speedup vs baseline: 1.3241x; 1.0381x over previous
//
// CTRNN MI355X — R15: R14 minus ternary-select regression, v_rcp sigmoid, unroll-2 t-loop
#include <hip/hip_runtime.h>

#define T_STEPS 1024
#define BATCH   64
#define IDIM    128
#define HDIM    512
#define ALPHA_F 0.02f
#define NLOG2E  (-1.4426950408889634f)

typedef _Float16 half2_t __attribute__((ext_vector_type(2)));
typedef unsigned int uint32;

__device__ __forceinline__ float dot2f(uint32 w, uint32 h, float acc) {
#if __has_builtin(__builtin_amdgcn_fdot2)
  return __builtin_amdgcn_fdot2(__builtin_bit_cast(half2_t, w),
                                __builtin_bit_cast(half2_t, h), acc, false);
#else
  half2_t a = __builtin_bit_cast(half2_t, w);
  half2_t b = __builtin_bit_cast(half2_t, h);
  return acc + (float)a.x * (float)b.x + (float)a.y * (float)b.y;
#endif
}

__device__ __forceinline__ uint32 pk2(float a, float b) {
  auto p = __builtin_amdgcn_cvt_pkrtz(a, b);
  return __builtin_bit_cast(uint32, p);
}

__device__ __forceinline__ int dot4i8(uint32 a, uint32 b, int c) {
#if __has_builtin(__builtin_amdgcn_sdot4)
  return __builtin_amdgcn_sdot4((int)a, (int)b, c, false);
#else
  int s = c;
  s += (int)(signed char)(a)        * (int)(signed char)(b);
  s += (int)(signed char)(a >> 8)   * (int)(signed char)(b >> 8);
  s += (int)(signed char)(a >> 16)  * (int)(signed char)(b >> 16);
  s += (int)(signed char)(a >> 24)  * (int)(signed char)(b >> 24);
  return s;
#endif
}

__device__ __forceinline__ uint32 pkq(float v0, float v1, float v2, float v3, float inv) {
  int i0 = __float2int_rn(v0 * inv), i1 = __float2int_rn(v1 * inv);
  int i2 = __float2int_rn(v2 * inv), i3 = __float2int_rn(v3 * inv);
  return (uint32)(i0 & 255) | ((uint32)(i1 & 255) << 8) |
         ((uint32)(i2 & 255) << 16) | ((uint32)(i3 & 255) << 24);
}

// single-instruction v_rcp_f32 (full IEEE divide is ~8 serial insts without fast-math)
__device__ __forceinline__ float fast_rcp(float x) {
#if __has_builtin(__builtin_amdgcn_rcpf)
  return __builtin_amdgcn_rcpf(x);
#else
  return 1.0f / x;
#endif
}

__device__ __forceinline__ int dpp_xor1(int x) {
#if __has_builtin(__builtin_amdgcn_mov_dpp)
  return __builtin_amdgcn_mov_dpp(x, 0xB1, 0xF, 0xF, true);  // quad_perm [1,0,3,2]
#else
  return __shfl_xor(x, 1);
#endif
}
__device__ __forceinline__ int dpp_xor2(int x) {
#if __has_builtin(__builtin_amdgcn_mov_dpp)
  return __builtin_amdgcn_mov_dpp(x, 0x4E, 0xF, 0xF, true);  // quad_perm [2,3,0,1]
#else
  return __shfl_xor(x, 2);
#endif
}
__device__ __forceinline__ int swz_xor4(int x) {
#if __has_builtin(__builtin_amdgcn_ds_swizzle)
  return __builtin_amdgcn_ds_swizzle(x, 0x101F);  // BitMode xor=4
#else
  return __shfl_xor(x, 4);
#endif
}
__device__ __forceinline__ float fxor1(float x) {
  return __builtin_bit_cast(float, dpp_xor1(__builtin_bit_cast(int, x)));
}
__device__ __forceinline__ float fxor2(float x) {
  return __builtin_bit_cast(float, dpp_xor2(__builtin_bit_cast(int, x)));
}
__device__ __forceinline__ float fxor4(float x) {
  return __builtin_bit_cast(float, swz_xor4(__builtin_bit_cast(int, x)));
}

// ---------------------------------------------------------------------------
// x_proj kernel: xp[m][j] = NLOG2E * sum_i x[m][i] * Win[j][i]  (f16 dot2)
// ---------------------------------------------------------------------------
__global__ __launch_bounds__(512) void ctrnn_proj(
    const float* __restrict__ x,    // [rows][128]
    const float* __restrict__ Win,  // [512][128]
    float* __restrict__ xp,         // [rows][512], pre-scaled by -log2e
    int rows) {
  const int j = threadIdx.x;
  __shared__ __attribute__((aligned(16))) uint32 xb[8][64];

  uint32 w[64];
  const float2* wr = (const float2*)(Win + (size_t)j * IDIM);
#pragma unroll
  for (int p = 0; p < 64; ++p) {
    float2 f = wr[p];
    w[p] = pk2(f.x, f.y);
  }

  const int m0 = blockIdx.x * 128;
  for (int it = 0; it < 16; ++it) {
    const int mb = m0 + it * 8;
    __syncthreads();
    if (j < 256) {
      const int r = j >> 5, q = j & 31;
      const int m = mb + r;
      float4 v = make_float4(0.f, 0.f, 0.f, 0.f);
      if (m < rows) v = *(const float4*)(x + (size_t)m * IDIM + q * 4);
      xb[r][2 * q]     = pk2(v.x, v.y);
      xb[r][2 * q + 1] = pk2(v.z, v.w);
    }
    __syncthreads();
#pragma unroll
    for (int r = 0; r < 8; ++r) {
      const int m = mb + r;
      if (m < rows) {
        const uint4* xv = (const uint4*)xb[r];
        float a0 = 0.f, a1 = 0.f, a2 = 0.f, a3 = 0.f;
#pragma unroll
        for (int c = 0; c < 16; ++c) {
          uint4 hx = xv[c];
          a0 = dot2f(w[4 * c + 0], hx.x, a0);
          a1 = dot2f(w[4 * c + 1], hx.y, a1);
          a2 = dot2f(w[4 * c + 2], hx.z, a2);
          a3 = dot2f(w[4 * c + 3], hx.w, a3);
        }
        xp[(size_t)m * HDIM + j] = NLOG2E * ((a0 + a1) + (a2 + a3));
      }
    }
  }
}

// ---------------------------------------------------------------------------
// scan kernel (R11 structure): 1 block/batch, 512 threads (2 waves/SIMD).
// thread j: g = j&7 (col-eighth, 64 cols = 16 i8 dwords), o = j>>3 (rows
// 8o..8o+7); acc slot i holds row 8o+(i^g); 7-exchange DPP/swizzle reduce;
// own row lands in slot 0. h mirror: i8, row r at byte r+16*(r>>6).
// R15 deltas vs R14: direct hb[c] fragment indexing (the R14 ternary chain
// risked surviving as cndmask selects ~200cy/step); v_rcp_f32 sigmoid (full
// IEEE divide is ~8 serial insts); #pragma unroll 2 on the t-loop.
// ---------------------------------------------------------------------------
__global__ __launch_bounds__(512)
__attribute__((amdgpu_waves_per_eu(2, 2)))
void ctrnn_scan(
    const float* __restrict__ xp,  // [ct][BATCH][HDIM], pre-scaled by -log2e
    const float* __restrict__ Wh,  // [512][512]
    const float* __restrict__ h0,  // [512]
    float* __restrict__ out,       // [T][B][H] then [B][H] final hidden
    int t0, int ct) {
  const int b = blockIdx.x;
  const int j = threadIdx.x;   // == output row n
  const int g = j & 7;
  const int o = j >> 3;

  __shared__ __attribute__((aligned(16))) unsigned char hq[2][640];

  // ---- pass 1: per-slot local absmax over 64 cols (slot i <-> row 8o+(i^g)) ----
  float m[8];
#pragma unroll
  for (int i = 0; i < 8; ++i) {
    const float4* wr = (const float4*)(Wh + (size_t)(8 * o + (i ^ g)) * HDIM + 64 * g);
    float mm = 0.f;
#pragma unroll
    for (int c = 0; c < 16; ++c) {
      float4 v = wr[c];
      mm = fmaxf(mm, fmaxf(fmaxf(fabsf(v.x), fabsf(v.y)), fmaxf(fabsf(v.z), fabsf(v.w))));
    }
    m[i] = mm;
  }
  {  // allreduce per row across the 8 lanes (slot-permuted partners)
    float t[8];
#pragma unroll
    for (int i = 0; i < 8; ++i) t[i] = fmaxf(m[i], fxor1(m[i ^ 1]));
#pragma unroll
    for (int i = 0; i < 8; ++i) m[i] = fmaxf(t[i], fxor2(t[i ^ 2]));
#pragma unroll
    for (int i = 0; i < 8; ++i) t[i] = fmaxf(m[i], fxor4(m[i ^ 4]));
#pragma unroll
    for (int i = 0; i < 8; ++i) m[i] = t[i];
  }

  // ---- pass 2: quantize 8 row-slices (16 dwords each) into w[128] ----
  uint32 w[128];
#pragma unroll
  for (int i = 0; i < 8; ++i) {
    const float rm = m[i];
    const float inv = (rm > 0.f) ? 127.f / rm : 0.f;
    const float4* wr = (const float4*)(Wh + (size_t)(8 * o + (i ^ g)) * HDIM + 64 * g);
#pragma unroll
    for (int c = 0; c < 16; ++c) {
      float4 v = wr[c];
      w[i * 16 + c] = pkq(v.x, v.y, v.z, v.w, inv);
    }
  }
  // afac = -log2e * fscale (own row == slot 0); xp already pre-scaled
  const float afac = m[0] * (1.f / (127.f * 127.f)) * NLOG2E;

  // ---- initial hidden: h (f32) in register, i8 mirror via b8 write ----
  float h;
  if (t0 == 0) h = h0[j];
  else h = out[((size_t)(t0 - 1) * BATCH + b) * HDIM + j];
  hq[0][j + 16 * (j >> 6)] = (unsigned char)(__float2int_rn(h * 127.f));
  __syncthreads();

  const float* xpp = xp + (size_t)b * HDIM + j;
  float* outp = out + ((size_t)t0 * BATCH + b) * HDIM + j;
  const size_t BH = (size_t)BATCH * HDIM;

  int cur = 0;
#pragma unroll 2
  for (int t = 0; t < ct; ++t) {
    const float xpw = *xpp;  // pre-scaled; L2 latency hides under dots

    const uint4* hb = (const uint4*)(&hq[cur][80 * g]);
    int a0 = 0, a1 = 0, a2 = 0, a3 = 0, a4 = 0, a5 = 0, a6 = 0, a7 = 0;
#pragma unroll
    for (int c = 0; c < 4; ++c) {
      const uint4 hv = hb[c];  // direct static index: no select chain
      a0 = dot4i8(w[0 * 16 + 4 * c + 0], hv.x, a0);
      a0 = dot4i8(w[0 * 16 + 4 * c + 1], hv.y, a0);
      a0 = dot4i8(w[0 * 16 + 4 * c + 2], hv.z, a0);
      a0 = dot4i8(w[0 * 16 + 4 * c + 3], hv.w, a0);
      a1 = dot4i8(w[1 * 16 + 4 * c + 0], hv.x, a1);
      a1 = dot4i8(w[1 * 16 + 4 * c + 1], hv.y, a1);
      a1 = dot4i8(w[1 * 16 + 4 * c + 2], hv.z, a1);
      a1 = dot4i8(w[1 * 16 + 4 * c + 3], hv.w, a1);
      a2 = dot4i8(w[2 * 16 + 4 * c + 0], hv.x, a2);
      a2 = dot4i8(w[2 * 16 + 4 * c + 1], hv.y, a2);
      a2 = dot4i8(w[2 * 16 + 4 * c + 2], hv.z, a2);
      a2 = dot4i8(w[2 * 16 + 4 * c + 3], hv.w, a2);
      a3 = dot4i8(w[3 * 16 + 4 * c + 0], hv.x, a3);
      a3 = dot4i8(w[3 * 16 + 4 * c + 1], hv.y, a3);
      a3 = dot4i8(w[3 * 16 + 4 * c + 2], hv.z, a3);
      a3 = dot4i8(w[3 * 16 + 4 * c + 3], hv.w, a3);
      a4 = dot4i8(w[4 * 16 + 4 * c + 0], hv.x, a4);
      a4 = dot4i8(w[4 * 16 + 4 * c + 1], hv.y, a4);
      a4 = dot4i8(w[4 * 16 + 4 * c + 2], hv.z, a4);
      a4 = dot4i8(w[4 * 16 + 4 * c + 3], hv.w, a4);
      a5 = dot4i8(w[5 * 16 + 4 * c + 0], hv.x, a5);
      a5 = dot4i8(w[5 * 16 + 4 * c + 1], hv.y, a5);
      a5 = dot4i8(w[5 * 16 + 4 * c + 2], hv.z, a5);
      a5 = dot4i8(w[5 * 16 + 4 * c + 3], hv.w, a5);
      a6 = dot4i8(w[6 * 16 + 4 * c + 0], hv.x, a6);
      a6 = dot4i8(w[6 * 16 + 4 * c + 1], hv.y, a6);
      a6 = dot4i8(w[6 * 16 + 4 * c + 2], hv.z, a6);
      a6 = dot4i8(w[6 * 16 + 4 * c + 3], hv.w, a6);
      a7 = dot4i8(w[7 * 16 + 4 * c + 0], hv.x, a7);
      a7 = dot4i8(w[7 * 16 + 4 * c + 1], hv.y, a7);
      a7 = dot4i8(w[7 * 16 + 4 * c + 2], hv.z, a7);
      a7 = dot4i8(w[7 * 16 + 4 * c + 3], hv.w, a7);
    }
    // 7-exchange tree (own row ends in slot 0)
    const int q0 = a0 + dpp_xor1(a1);
    const int q1 = a2 + dpp_xor1(a3);
    const int q2 = a4 + dpp_xor1(a5);
    const int q3 = a6 + dpp_xor1(a7);
    const int r0 = q0 + dpp_xor2(q1);
    const int r1 = q2 + dpp_xor2(q3);
    const int res = r0 + swz_xor4(r1);

    // sigmoid via exp2 + single-inst rcp: e = 2^(afac*res + xpw) == e^{-z}
    const float e = exp2f((float)res * afac + xpw);
    const float s = fast_rcp(1.0f + e);
    h = h * (1.0f - ALPHA_F) + s * ALPHA_F;

    // i8 mirror write (single byte) BEFORE barrier
    hq[cur ^ 1][j + 16 * (j >> 6)] = (unsigned char)(__float2int_rn(h * 127.f));
    __syncthreads();

    *outp = h;  // after barrier: issues in the shadow of next step's dots
    cur ^= 1;
    xpp += BH;
    outp += BH;
  }

  if (t0 + ct == T_STEPS) {
    out[(size_t)T_STEPS * BATCH * HDIM + (size_t)b * HDIM + j] = h;
  }
}

// ---------------------------------------------------------------------------
extern "C" void kernel_launch(void* const* d_in, const int* in_sizes, int n_in,
                              void* d_out, int out_size, void* d_ws, size_t ws_size,
                              hipStream_t stream) {
  const float* x   = (const float*)d_in[0];
  const float* Win = (const float*)d_in[1];
  const float* Wh  = (const float*)d_in[2];
  const float* h0  = (const float*)d_in[3];
  float* out = (float*)d_out;
  float* xp  = (float*)d_ws;

  const size_t step_bytes = (size_t)BATCH * HDIM * sizeof(float);  // 128 KB
  int ct_max = (int)(ws_size / step_bytes);
  if (ct_max < 1) ct_max = 1;
  if (ct_max > T_STEPS) ct_max = T_STEPS;

  for (int t0 = 0; t0 < T_STEPS; t0 += ct_max) {
    const int ct = (T_STEPS - t0 < ct_max) ? (T_STEPS - t0) : ct_max;
    const int rows = ct * BATCH;
    const int nb = (rows + 127) / 128;
    hipLaunchKernelGGL(ctrnn_proj, dim3(nb), dim3(512), 0, stream,
                       x + (size_t)t0 * BATCH * IDIM, Win, xp, rows);
    hipLaunchKernelGGL(ctrnn_scan, dim3(BATCH), dim3(512), 0, stream,
                       xp, Wh, h0, out, t0, ct);
  }
}